// Round 6
// baseline (481.435 us; speedup 1.0000x reference)
//
#include <hip/hip_runtime.h>
#include <hip/hip_bf16.h>
#include <hip/hip_cooperative_groups.h>
#include <stdint.h>

namespace cg = cooperative_groups;

#define N_USERS   10000
#define N_ITEMS   100000
#define N_FEAT    64
#define EMB_DIM   128
#define SEQ_LEN   50
#define TAU       0.01f
#define N_CU      256

typedef float f32x4 __attribute__((ext_vector_type(4)));   // native clang vector

__device__ inline f32x4 nt_load4(const float* p) {
    return __builtin_nontemporal_load(reinterpret_cast<const f32x4*>(p));
}

// ---- shared device helpers ------------------------------------------------

// mask dtype detection (uniform across grid): 0=int32, 1=fp32, 2=byte bool
__device__ inline int detect_mask_mode(const void* mask_raw, int lane) {
    const unsigned int* mi = (const unsigned int*)mask_raw;
    unsigned int pv = mi[lane];
    float        pf = __uint_as_float(pv);
    bool allint = __all(pv <= 1u) != 0;
    bool allflt = __all(pf == 0.0f || pf == 1.0f) != 0;
    return allint ? 0 : (allflt ? 1 : 2);
}

__device__ inline unsigned long long load_mask_ballot(
    const void* mask_raw, int mode, int n, int lane)
{
    bool mv = false;
    if (lane < SEQ_LEN) {
        size_t off = (size_t)n * SEQ_LEN + lane;
        if (mode == 0)      mv = ((const int*)mask_raw)[off] != 0;
        else if (mode == 1) mv = ((const float*)mask_raw)[off] != 0.0f;
        else                mv = ((const uint8_t*)mask_raw)[off] != 0;
    }
    return __ballot(mv);
}

// phase-1 body: compute wt for sequence n and scatter into num/den
__device__ inline void wt_scatter_seq(
    int n, int lane, int f4, int sg, f32x4 w4,
    const float* __restrict__ R, unsigned long long mbits,
    float alpha, float beta, float gamma,
    const int* __restrict__ users, const int* __restrict__ items,
    const float* __restrict__ item_emb,
    float* __restrict__ num, float* __restrict__ den)
{
    const int u  = users[n];
    const int it = items[n];
    const float* Rn = R + (size_t)n * SEQ_LEN * N_FEAT;

    float acc = 0.0f;   // identical across the 16 lanes of a step-group
    float cnt = 0.0f;

    #pragma unroll
    for (int s0 = 0; s0 < SEQ_LEN; s0 += 4) {
        int s = s0 + sg;
        bool valid = (s < SEQ_LEN);
        f32x4 x = {0.f, 0.f, 0.f, 0.f};
        if (valid) x = nt_load4(Rn + s * N_FEAT + 4 * f4);   // streamed once
        float d = x.x * w4.x + x.y * w4.y + x.z * w4.z + x.w * w4.w;
        d += __shfl_xor(d, 1);
        d += __shfl_xor(d, 2);
        d += __shfl_xor(d, 4);
        d += __shfl_xor(d, 8);
        if (valid && ((mbits >> s) & 1ULL)) {
            float Wv = fmaxf(d, TAU);
            acc += (alpha == 1.0f) ? Wv : powf(Wv, alpha);
            cnt += 1.0f;
        }
    }
    acc += __shfl_xor(acc, 16);
    acc += __shfl_xor(acc, 32);
    cnt += __shfl_xor(cnt, 16);
    cnt += __shfl_xor(cnt, 32);

    float W_alpha = (alpha == 1.0f) ? acc : powf(acc, 1.0f / alpha);
    float R_beta  = (beta  == 1.0f) ? cnt : powf(cnt, beta);
    float base    = W_alpha * R_beta;
    float wt      = (gamma == 1.0f) ? base : powf(base, gamma);

    const float2 q = reinterpret_cast<const float2*>(item_emb + (size_t)it * EMB_DIM)[lane];
    float* numrow = num + (size_t)u * EMB_DIM;
    atomicAdd(&numrow[2 * lane],     wt * q.x);
    atomicAdd(&numrow[2 * lane + 1], wt * q.y);
    if (lane == 0) atomicAdd(&den[u], wt);
}

// phase-2 body: r[n] = dot(num[u], q[n]) / den[u]
__device__ inline void final_seq(
    int n, int lane,
    const int* __restrict__ users, const int* __restrict__ items,
    const float* __restrict__ item_emb,
    const float* __restrict__ num, const float* __restrict__ den,
    float* __restrict__ r)
{
    int u  = users[n];
    int it = items[n];
    float2 q = reinterpret_cast<const float2*>(item_emb + (size_t)it * EMB_DIM)[lane];
    float2 p = reinterpret_cast<const float2*>(num + (size_t)u * EMB_DIM)[lane];
    float dot = q.x * p.x + q.y * p.y;
    dot += __shfl_xor(dot, 1);
    dot += __shfl_xor(dot, 2);
    dot += __shfl_xor(dot, 4);
    dot += __shfl_xor(dot, 8);
    dot += __shfl_xor(dot, 16);
    dot += __shfl_xor(dot, 32);
    if (lane == 0) r[n] = dot / den[u];
}

// ---------------------------------------------------------------------------
// Cooperative fused kernel: phase 1 (grid-stride) -> grid.sync -> phase 2.
// Grid is sized by the runtime occupancy query in kernel_launch.
// ---------------------------------------------------------------------------
__global__ __launch_bounds__(256, 4) void fused_kernel(
    const float* __restrict__ R, const void* __restrict__ mask_raw,
    const float* __restrict__ w,
    const int* __restrict__ users, const int* __restrict__ items,
    const float* __restrict__ item_emb,
    const float* __restrict__ alpha_p, const float* __restrict__ beta_p,
    const float* __restrict__ gamma_p,
    float* __restrict__ num, float* __restrict__ den,
    float* __restrict__ r, int num_seq)
{
    cg::grid_group grid = cg::this_grid();

    const int lane   = threadIdx.x & 63;
    const int wib    = threadIdx.x >> 6;
    const int wpb    = blockDim.x >> 6;
    const int gwave  = blockIdx.x * wpb + wib;
    const int nwaves = gridDim.x * wpb;

    const int mode = detect_mask_mode(mask_raw, lane);

    const float alpha = alpha_p[0];
    const float beta  = beta_p[0];
    const float gamma = gamma_p[0];

    const int f4 = lane & 15;
    const int sg = lane >> 4;
    const f32x4 w4 = *reinterpret_cast<const f32x4*>(w + 4 * f4);

    for (int n = gwave; n < num_seq; n += nwaves) {
        unsigned long long mbits = load_mask_ballot(mask_raw, mode, n, lane);
        wt_scatter_seq(n, lane, f4, sg, w4, R, mbits, alpha, beta, gamma,
                       users, items, item_emb, num, den);
    }

    grid.sync();

    for (int n = gwave; n < num_seq; n += nwaves) {
        final_seq(n, lane, users, items, item_emb, num, den, r);
    }
}

// ---------------------------------------------------------------------------
// Fallback path (round-4 proven): two ordinary kernels.
// ---------------------------------------------------------------------------
__global__ __launch_bounds__(256) void wt_scatter_kernel(
    const float* __restrict__ R, const void* __restrict__ mask_raw,
    const float* __restrict__ w,
    const int* __restrict__ users, const int* __restrict__ items,
    const float* __restrict__ item_emb,
    const float* __restrict__ alpha_p, const float* __restrict__ beta_p,
    const float* __restrict__ gamma_p,
    float* __restrict__ num, float* __restrict__ den, int num_seq)
{
    int wave = (blockIdx.x * blockDim.x + threadIdx.x) >> 6;
    int lane = threadIdx.x & 63;
    if (wave >= num_seq) return;
    const int n = wave;

    const int mode = detect_mask_mode(mask_raw, lane);
    unsigned long long mbits = load_mask_ballot(mask_raw, mode, n, lane);

    const float alpha = alpha_p[0];
    const float beta  = beta_p[0];
    const float gamma = gamma_p[0];

    const int f4 = lane & 15;
    const int sg = lane >> 4;
    const f32x4 w4 = *reinterpret_cast<const f32x4*>(w + 4 * f4);

    wt_scatter_seq(n, lane, f4, sg, w4, R, mbits, alpha, beta, gamma,
                   users, items, item_emb, num, den);
}

__global__ __launch_bounds__(256) void final_kernel(
    const int* __restrict__ users, const int* __restrict__ items,
    const float* __restrict__ item_emb,
    const float* __restrict__ num, const float* __restrict__ den,
    float* __restrict__ r, int num_seq)
{
    int wave = (blockIdx.x * blockDim.x + threadIdx.x) >> 6;
    int lane = threadIdx.x & 63;
    if (wave >= num_seq) return;
    final_seq(wave, lane, users, items, item_emb, num, den, r);
}

extern "C" void kernel_launch(void* const* d_in, const int* in_sizes, int n_in,
                              void* d_out, int out_size, void* d_ws, size_t ws_size,
                              hipStream_t stream)
{
    const int*   users    = (const int*)d_in[0];
    const int*   items    = (const int*)d_in[1];
    const float* R_ui     = (const float*)d_in[2];
    const void*  mask     = d_in[3];              // dtype detected on device
    const float* w        = (const float*)d_in[4];
    const float* item_emb = (const float*)d_in[5];
    const float* alpha    = (const float*)d_in[6];
    const float* beta     = (const float*)d_in[7];
    const float* gamma    = (const float*)d_in[8];

    int num_seq = in_sizes[0];                // 100000
    float* num = (float*)d_ws;                              // [N_USERS][EMB_DIM]
    float* den = (float*)d_ws + (size_t)N_USERS * EMB_DIM;  // [N_USERS]
    float* rout = (float*)d_out;

    // zero the per-user accumulators (graph-capture-safe async memset)
    (void)hipMemsetAsync(d_ws, 0,
                         ((size_t)N_USERS * EMB_DIM + N_USERS) * sizeof(float),
                         stream);

    // ---- try the cooperative fused path, sized by the runtime's own query ----
    hipError_t cerr = hipErrorUnknown;
    int maxBlocksPerCU = 0;
    hipError_t qerr = hipOccupancyMaxActiveBlocksPerMultiprocessor(
        &maxBlocksPerCU, fused_kernel, 256, 0);
    if (qerr == hipSuccess && maxBlocksPerCU > 0) {
        int grid = maxBlocksPerCU * N_CU;
        if (grid > 2048) grid = 2048;
        void* args[] = {
            (void*)&R_ui, (void*)&mask, (void*)&w,
            (void*)&users, (void*)&items, (void*)&item_emb,
            (void*)&alpha, (void*)&beta, (void*)&gamma,
            (void*)&num, (void*)&den, (void*)&rout, (void*)&num_seq,
        };
        cerr = hipLaunchCooperativeKernel((const void*)fused_kernel,
                                          dim3(grid), dim3(256), args, 0, stream);
    }

    if (cerr != hipSuccess) {
        // ---- fallback: proven two-kernel path ----
        int waves_per_block = 4;
        int blocks = (num_seq + waves_per_block - 1) / waves_per_block;
        wt_scatter_kernel<<<blocks, 256, 0, stream>>>(R_ui, mask, w, users, items,
                                                      item_emb, alpha, beta, gamma,
                                                      num, den, num_seq);
        final_kernel<<<blocks, 256, 0, stream>>>(users, items, item_emb,
                                                 num, den, rout, num_seq);
    }
}

// Round 7
// 274.327 us; speedup vs baseline: 1.7550x; 1.7550x over previous
//
#include <hip/hip_runtime.h>
#include <hip/hip_bf16.h>
#include <stdint.h>

#define N_USERS   10000
#define N_ITEMS   100000
#define N_FEAT    64
#define EMB_DIM   128
#define SEQ_LEN   50
#define TAU       0.01f

typedef float f32x4 __attribute__((ext_vector_type(4)));   // native clang vector

__device__ inline f32x4 nt_load4(const float* p) {
    return __builtin_nontemporal_load(reinterpret_cast<const f32x4*>(p));
}

// ---- shared device helpers ------------------------------------------------

// mask dtype detection (uniform across grid): 0=int32, 1=fp32, 2=byte bool
__device__ inline int detect_mask_mode(const void* mask_raw, int lane) {
    const unsigned int* mi = (const unsigned int*)mask_raw;
    unsigned int pv = mi[lane];
    float        pf = __uint_as_float(pv);
    bool allint = __all(pv <= 1u) != 0;
    bool allflt = __all(pf == 0.0f || pf == 1.0f) != 0;
    return allint ? 0 : (allflt ? 1 : 2);
}

__device__ inline unsigned long long load_mask_ballot(
    const void* mask_raw, int mode, int n, int lane)
{
    bool mv = false;
    if (lane < SEQ_LEN) {
        size_t off = (size_t)n * SEQ_LEN + lane;
        if (mode == 0)      mv = ((const int*)mask_raw)[off] != 0;
        else if (mode == 1) mv = ((const float*)mask_raw)[off] != 0.0f;
        else                mv = ((const uint8_t*)mask_raw)[off] != 0;
    }
    return __ballot(mv);
}

// ---------------------------------------------------------------------------
// Kernel 1 (fused): per-sequence weight wt + atomic scatter into num/den.
// One wave per sequence: 13 independent fully-unrolled 1KB wave-loads
// (max memory parallelism for the 1.28 GB R stream, nontemporal).
// ---------------------------------------------------------------------------
__global__ __launch_bounds__(256) void wt_scatter_kernel(
    const float* __restrict__ R, const void* __restrict__ mask_raw,
    const float* __restrict__ w,
    const int* __restrict__ users, const int* __restrict__ items,
    const float* __restrict__ item_emb,
    const float* __restrict__ alpha_p, const float* __restrict__ beta_p,
    const float* __restrict__ gamma_p,
    float* __restrict__ num, float* __restrict__ den, int num_seq)
{
    int wave = (blockIdx.x * blockDim.x + threadIdx.x) >> 6;
    int lane = threadIdx.x & 63;
    if (wave >= num_seq) return;   // whole waves retire together
    const int n = wave;

    // hoist per-sequence scalars early (latency hidden under the stream)
    const int u  = users[n];
    const int it = items[n];

    const int mode = detect_mask_mode(mask_raw, lane);
    unsigned long long mbits = load_mask_ballot(mask_raw, mode, n, lane);

    const float alpha = alpha_p[0];
    const float beta  = beta_p[0];
    const float gamma = gamma_p[0];

    const int f4 = lane & 15;   // which float4 of the 64 features
    const int sg = lane >> 4;   // which of 4 concurrent steps
    const f32x4 w4 = *reinterpret_cast<const f32x4*>(w + 4 * f4);
    const float* Rn = R + (size_t)n * SEQ_LEN * N_FEAT;

    float acc = 0.0f;   // identical across the 16 lanes of a step-group
    float cnt = 0.0f;

    #pragma unroll
    for (int s0 = 0; s0 < SEQ_LEN; s0 += 4) {
        int s = s0 + sg;
        bool valid = (s < SEQ_LEN);
        f32x4 x = {0.f, 0.f, 0.f, 0.f};
        if (valid) x = nt_load4(Rn + s * N_FEAT + 4 * f4);   // streamed once
        float d = x.x * w4.x + x.y * w4.y + x.z * w4.z + x.w * w4.w;
        // butterfly over the 16 lanes sharing this step (DPP-lowered)
        d += __shfl_xor(d, 1);
        d += __shfl_xor(d, 2);
        d += __shfl_xor(d, 4);
        d += __shfl_xor(d, 8);
        if (valid && ((mbits >> s) & 1ULL)) {
            float Wv = fmaxf(d, TAU);
            acc += (alpha == 1.0f) ? Wv : powf(Wv, alpha);
            cnt += 1.0f;
        }
    }
    // sum the 4 step-groups; afterwards ALL lanes hold the full totals
    acc += __shfl_xor(acc, 16);
    acc += __shfl_xor(acc, 32);
    cnt += __shfl_xor(cnt, 16);
    cnt += __shfl_xor(cnt, 32);

    float W_alpha = (alpha == 1.0f) ? acc : powf(acc, 1.0f / alpha);
    float R_beta  = (beta  == 1.0f) ? cnt : powf(cnt, beta);
    float base    = W_alpha * R_beta;
    float wt      = (gamma == 1.0f) ? base : powf(base, gamma);

    // fused scatter: each lane owns 2 emb dims
    const float2 q = reinterpret_cast<const float2*>(item_emb + (size_t)it * EMB_DIM)[lane];
    float* numrow = num + (size_t)u * EMB_DIM;
    atomicAdd(&numrow[2 * lane],     wt * q.x);
    atomicAdd(&numrow[2 * lane + 1], wt * q.y);
    if (lane == 0) atomicAdd(&den[u], wt);
}

// ---------------------------------------------------------------------------
// Kernel 2: r[n] = dot(num[u], q[n]) / den[u].  One wave per sequence,
// lane owns 2 emb dims; num/item_emb reads are L2/L3-warm after kernel 1.
// ---------------------------------------------------------------------------
__global__ __launch_bounds__(512) void final_kernel(
    const int* __restrict__ users, const int* __restrict__ items,
    const float* __restrict__ item_emb,
    const float* __restrict__ num, const float* __restrict__ den,
    float* __restrict__ r, int num_seq)
{
    int wave = (blockIdx.x * blockDim.x + threadIdx.x) >> 6;
    int lane = threadIdx.x & 63;
    if (wave >= num_seq) return;
    const int n = wave;

    int u  = users[n];
    int it = items[n];
    float dinv = den[u];   // issue early; latency hides under the reduction
    float2 q = reinterpret_cast<const float2*>(item_emb + (size_t)it * EMB_DIM)[lane];
    float2 p = reinterpret_cast<const float2*>(num + (size_t)u * EMB_DIM)[lane];
    float dot = q.x * p.x + q.y * p.y;
    dot += __shfl_xor(dot, 1);
    dot += __shfl_xor(dot, 2);
    dot += __shfl_xor(dot, 4);
    dot += __shfl_xor(dot, 8);
    dot += __shfl_xor(dot, 16);
    dot += __shfl_xor(dot, 32);
    if (lane == 0) r[n] = dot / dinv;
}

extern "C" void kernel_launch(void* const* d_in, const int* in_sizes, int n_in,
                              void* d_out, int out_size, void* d_ws, size_t ws_size,
                              hipStream_t stream)
{
    const int*   users    = (const int*)d_in[0];
    const int*   items    = (const int*)d_in[1];
    const float* R_ui     = (const float*)d_in[2];
    const void*  mask     = d_in[3];              // dtype detected on device
    const float* w        = (const float*)d_in[4];
    const float* item_emb = (const float*)d_in[5];
    const float* alpha    = (const float*)d_in[6];
    const float* beta     = (const float*)d_in[7];
    const float* gamma    = (const float*)d_in[8];

    const int num_seq = in_sizes[0];          // 100000
    float* num = (float*)d_ws;                              // [N_USERS][EMB_DIM]
    float* den = (float*)d_ws + (size_t)N_USERS * EMB_DIM;  // [N_USERS]

    // zero the per-user accumulators (graph-capture-safe async memset)
    (void)hipMemsetAsync(d_ws, 0,
                         ((size_t)N_USERS * EMB_DIM + N_USERS) * sizeof(float),
                         stream);

    {   // kernel 1 (fused wt + scatter): one wave per sequence, 4 waves/block
        int waves_per_block = 4;
        int blocks = (num_seq + waves_per_block - 1) / waves_per_block;
        wt_scatter_kernel<<<blocks, 256, 0, stream>>>(R_ui, mask, w, users, items,
                                                      item_emb, alpha, beta, gamma,
                                                      num, den, num_seq);
    }
    {   // kernel 2: one wave per sequence, 8 waves/block
        int waves_per_block = 8;
        int blocks = (num_seq + waves_per_block - 1) / waves_per_block;
        final_kernel<<<blocks, 512, 0, stream>>>(users, items, item_emb,
                                                 num, den, (float*)d_out, num_seq);
    }
}